// Round 15
// baseline (121.783 us; speedup 1.0000x reference)
//
#include <hip/hip_runtime.h>
#include <hip/hip_bf16.h>

// Chamfer distance, B=4, N=M=8192, D=3, fp32.
// R14: (1) pin the min-accumulator in VGPRs: acc[nt] is an (unused) "+v"
// operand of the MFMA asm blob, so the register allocator cannot park it in
// AGPRs (R10-R13: VGPR_Count=52 proved acc was in AGPRs -> every fold was
// v_accvgpr_read + v_min3 + v_accvgpr_write, ~3x the VALU cost). WNT=2 keeps
// the pinned budget ~112 VGPR -> 4 waves/SIMD (2048 blocks).
// (2) in-kernel finalization (R12's verified poison-counter pattern,
// distributed): per-(dir,nch) ws counter (poison 0xAAAAAAAA) -> 8th block of
// each group min-reduces its 256 queries across the 8 ms slices (agent-scope
// loads), adds the partial mean to a ws float accumulator; global counter ->
// last group writes out[0]. Graph: ONE kernel node, zero memsets.
// Payload & MFMA blob numerics unchanged (absmax 0.0 since R7).
//   payload k0..15 (target A x query B): -2h.h | -2l.h | -2h.l | qn.1 | 1.tn

typedef __attribute__((ext_vector_type(8)))  short short8;
typedef __attribute__((ext_vector_type(16))) float f32x16;

#define BATCH 4
#define NPTS 8192
#define TOTALQ (BATCH * NPTS)   // 32768
#define BLK 256
#define WNT 2                   // 32-col B tiles per wave -> 64 queries/wave
#define BCOLS 256               // query cols per block (4 waves)
#define NCH (TOTALQ / BCOLS)    // 128 query chunks
#define MSPLIT 8                // target slices per batch
#define MC (NPTS / MSPLIT)      // 1024 targets per block, single LDS stage
#define MT_PER (MC / 32)        // 32 target tiles
#define NGROUPS (2 * NCH)       // 256 (dir, nch) groups
#define POISON_U 0xAAAAAAAAu

__device__ __forceinline__ unsigned short f2bf(float f) {  // RTN-even
    unsigned int u = __float_as_uint(f);
    u += 0x7FFFu + ((u >> 16) & 1u);
    return (unsigned short)(u >> 16);
}
__device__ __forceinline__ float bf2f(unsigned short h) {
    return __uint_as_float(((unsigned int)h) << 16);
}
__device__ __forceinline__ unsigned int pk2(unsigned short a, unsigned short b) {
    return (unsigned int)a | ((unsigned int)b << 16);
}

struct Payload {
    unsigned short hx, hy, hz, lx, ly, lz, n1, n2, n3;
};
__device__ __forceinline__ Payload split_point(float x, float y, float z) {
    Payload P;
    P.hx = f2bf(x);  P.hy = f2bf(y);  P.hz = f2bf(z);
    P.lx = f2bf(x - bf2f(P.hx));
    P.ly = f2bf(y - bf2f(P.hy));
    P.lz = f2bf(z - bf2f(P.hz));
    float nrm = fmaf(z, z, fmaf(y, y, x * x));
    P.n1 = f2bf(nrm);
    float r1 = nrm - bf2f(P.n1);
    P.n2 = f2bf(r1);
    P.n3 = f2bf(r1 - bf2f(P.n2));
    return P;
}

__global__ __launch_bounds__(BLK) void chamfer_mega_kernel(
        const float* __restrict__ pred, const float* __restrict__ target,
        float* __restrict__ part, unsigned int* __restrict__ grpcnt,
        float* __restrict__ wsacc, unsigned int* __restrict__ gcnt,
        float* __restrict__ out)
{
    const int dir = blockIdx.z;
    const float* __restrict__ Q  = dir ? target : pred;   // outputs (B cols)
    const float* __restrict__ Tg = dir ? pred : target;   // min-over (A, LDS)

    const int nch = blockIdx.x;            // 0..127 (256-query chunk)
    const int b   = nch >> 5;              // batch (32 chunks per batch)
    const int ms  = blockIdx.y;            // 0..7 target slice
    const int w    = threadIdx.x >> 6;
    const int lane = threadIdx.x & 63;
    const int c = lane & 31;               // row (A) / col (B) within tile
    const int g = lane >> 5;               // k-half
    const unsigned short ONE = 0x3F80;

    __shared__ uint4 ldsb[2][MC];          // 32 KB (two k-halves)
    __shared__ float bsum[4];
    __shared__ int   fin;

    // ---- stage MC target points: raw read -> payload -> LDS (A operand) ----
    #pragma unroll
    for (int j = 0; j < MC / BLK; ++j) {
        int p = j * BLK + threadIdx.x;
        size_t gp = (size_t)b * NPTS + (size_t)ms * MC + p;
        float x = Tg[3 * gp], y = Tg[3 * gp + 1], z = Tg[3 * gp + 2];
        Payload P = split_point(x, y, z);
        ldsb[0][p] = (uint4){ pk2(P.hx, P.hy), pk2(P.hz, P.hx),
                              pk2(P.hy, P.hz), pk2(P.lx, P.ly) };
        ldsb[1][p] = (uint4){ pk2(P.lz, ONE), pk2(ONE, ONE),
                              pk2(P.n1, P.n2), pk2(P.n3, 0) };
    }

    // ---- B fragments (queries): in-register pack ----
    const int colstart = nch * BCOLS + w * (WNT * 32);
    short8 bq[WNT];
    #pragma unroll
    for (int nt = 0; nt < WNT; ++nt) {
        int r = colstart + nt * 32 + c;
        float x = Q[3 * r], y = Q[3 * r + 1], z = Q[3 * r + 2];
        Payload P = split_point(x, y, z);
        unsigned short ax = f2bf(-2.f * bf2f(P.hx)),
                       ay = f2bf(-2.f * bf2f(P.hy)),
                       az = f2bf(-2.f * bf2f(P.hz));
        unsigned short cx = f2bf(-2.f * bf2f(P.lx)),
                       cy = f2bf(-2.f * bf2f(P.ly)),
                       cz = f2bf(-2.f * bf2f(P.lz));
        uint4 h0 = { pk2(ax, ay), pk2(az, cx), pk2(cy, cz), pk2(ax, ay) };
        uint4 h1 = { pk2(az, P.n1), pk2(P.n2, P.n3), pk2(ONE, ONE), pk2(ONE, 0) };
        uint4 sel = g ? h1 : h0;
        bq[nt] = *(short8*)&sel;
    }

    f32x16 acc[WNT];
    #pragma unroll
    for (int nt = 0; nt < WNT; ++nt)
        #pragma unroll
        for (int r = 0; r < 16; ++r) acc[nt][r] = 3.4e38f;

    f32x16 vzero;
    #pragma unroll
    for (int r = 0; r < 16; ++r) vzero[r] = 0.0f;

    __syncthreads();

    const ushort* ldsu = (const ushort*)&ldsb[g][0];   // this lane's k-half

    // ---- main loop: 2 ds_read_b128 + 4 MFMA + 32 pure-VGPR min3 ----
    #pragma unroll 2
    for (int mt = 0; mt < MT_PER; mt += 2) {
        short8 at0 = *(const short8*)(ldsu + (mt * 32 + c) * 8);
        short8 at1 = *(const short8*)(ldsu + ((mt + 1) * 32 + c) * 8);
        #pragma unroll
        for (int nt = 0; nt < WNT; ++nt) {
            f32x16 d0, d1;
            // %0 (acc) is textually unused: the "+v" constraint pins the
            // accumulator into VGPRs so the fold below is v_min3 with no
            // v_accvgpr_read/write traffic. s_nop pads MFMA->VALU hazard.
            asm("v_mfma_f32_32x32x16_bf16 %1, %3, %5, %6\n\t"
                "v_mfma_f32_32x32x16_bf16 %2, %4, %5, %6\n\t"
                "s_nop 7\n\t"
                "s_nop 7"
                : "+v"(acc[nt]), "=&v"(d0), "=&v"(d1)
                : "v"(at0), "v"(at1), "v"(bq[nt]), "v"(vzero));
            #pragma unroll
            for (int r = 0; r < 16; ++r)
                acc[nt][r] = fminf(fminf(acc[nt][r], d0[r]), d1[r]); // v_min3
        }
    }

    // ---- epilogue: in-lane fold + 1 shfl; store slice partials ----
    float* rp = part + (size_t)(dir * MSPLIT + ms) * TOTALQ;
    #pragma unroll
    for (int nt = 0; nt < WNT; ++nt) {
        f32x16 v = acc[nt];
        float m0 = fminf(fminf(v[0],  v[1]),  fminf(v[2],  v[3]));
        float m1 = fminf(fminf(v[4],  v[5]),  fminf(v[6],  v[7]));
        float m2 = fminf(fminf(v[8],  v[9]),  fminf(v[10], v[11]));
        float m3 = fminf(fminf(v[12], v[13]), fminf(v[14], v[15]));
        float m  = fminf(fminf(m0, m1), fminf(m2, m3));
        m = fminf(m, __shfl_xor(m, 32, 64));
        if (g == 0) rp[colstart + nt * 32 + c] = m;
    }

    // ---- group finalization: 8th block of (dir,nch) reduces the group ----
    __syncthreads();
    if (threadIdx.x == 0) {
        __threadfence();                                   // release stores
        unsigned int old = atomicAdd(&grpcnt[dir * NCH + nch], 1u);
        fin = (old == POISON_U + (MSPLIT - 1)) ? 1 : 0;
    }
    __syncthreads();
    if (!fin) return;

    __threadfence();                                       // acquire
    {
        int qi = nch * BCOLS + threadIdx.x;                // one query/thread
        const float* p = part + (size_t)dir * MSPLIT * TOTALQ + qi;
        float m = __hip_atomic_load(&p[0], __ATOMIC_RELAXED,
                                    __HIP_MEMORY_SCOPE_AGENT);
        #pragma unroll
        for (int s = 1; s < MSPLIT; ++s)
            m = fminf(m, __hip_atomic_load(&p[(size_t)s * TOTALQ],
                                           __ATOMIC_RELAXED,
                                           __HIP_MEMORY_SCOPE_AGENT));
        float v = m * (1.0f / (float)TOTALQ);
        #pragma unroll
        for (int off = 32; off > 0; off >>= 1)
            v += __shfl_down(v, off, 64);
        if (lane == 0) bsum[w] = v;
    }
    __syncthreads();
    if (threadIdx.x == 0) {
        float s = (bsum[0] + bsum[1]) + (bsum[2] + bsum[3]);
        atomicAdd(wsacc, s);               // ws float poison -3e-13 ~ 0
        __threadfence();                   // release
        unsigned int old = atomicAdd(gcnt, 1u);            // poison-based
        if (old == POISON_U + (NGROUPS - 1)) {
            __threadfence();               // acquire
            out[0] = __hip_atomic_load(wsacc, __ATOMIC_RELAXED,
                                       __HIP_MEMORY_SCOPE_AGENT);
        }
    }
}

extern "C" void kernel_launch(void* const* d_in, const int* in_sizes, int n_in,
                              void* d_out, int out_size, void* d_ws, size_t ws_size,
                              hipStream_t stream) {
    const float*  pred   = (const float*)d_in[0];
    const float*  target = (const float*)d_in[1];
    float*        out    = (float*)d_out;
    float*        part   = (float*)d_ws;                  // 2 MB of slice minima
    char*         tail   = (char*)d_ws + (size_t)2 * MSPLIT * TOTALQ * 4;
    unsigned int* grpcnt = (unsigned int*)tail;           // 256 uints (poison)
    float*        wsacc  = (float*)(tail + 1024);         // poison ~ -3e-13
    unsigned int* gcnt   = (unsigned int*)(tail + 1028);  // poison 0xAAAAAAAA

    dim3 grid(NCH, MSPLIT, 2);             // 128 x 8 x 2 = 2048 blocks
    hipLaunchKernelGGL(chamfer_mega_kernel, grid, dim3(BLK), 0, stream,
                       pred, target, part, grpcnt, wsacc, gcnt, out);
}

// Round 16
// 98.447 us; speedup vs baseline: 1.2370x; 1.2370x over previous
//
#include <hip/hip_runtime.h>
#include <hip/hip_bf16.h>

// Chamfer distance, B=4, N=M=8192, D=3, fp32.
// R15: R11's exact geometry + main loop (best measured: mega ~21 us, total
// 77.6) + in-kernel finalization (R12/R14-verified poison-counter pattern)
// to delete the reduce node and its dispatch gap. R14's regression is
// attributed (counters) to WNT=2 staging doubling + "+v" tie copies, NOT the
// finalization; so keep WNT=4, untied asm blob, 64x8x2 grid.
// Finalization: per-(dir,nch) ws counter (poison 0xAAAAAAAA) -> 8th block of
// the group min-reduces its 512 queries across 8 ms slices (agent loads),
// atomicAdds the partial mean into ws float (poison -3e-13, negligible);
// global counter -> 128th group writes out[0]. 1 node, 0 memsets.
// Payload k0..15 (target A x query B): -2h.h | -2l.h | -2h.l | qn.1 | 1.tn
// (absmax 0.0 since R7). C/D 32x32 (m74/m101): col=lane&31,
// row=(reg&3)+8*(reg>>2)+4*(lane>>5).

typedef __attribute__((ext_vector_type(8)))  short short8;
typedef __attribute__((ext_vector_type(16))) float f32x16;

#define BATCH 4
#define NPTS 8192
#define TOTALQ (BATCH * NPTS)   // 32768
#define BLK 256
#define WNT 4                   // 32-col B tiles per wave -> 128 queries/wave
#define BCOLS 512               // query cols per block (4 waves)
#define NCH (TOTALQ / BCOLS)    // 64 query chunks
#define MSPLIT 8                // target slices per batch
#define MC (NPTS / MSPLIT)      // 1024 targets per block, single LDS stage
#define MT_PER (MC / 32)        // 32 target tiles
#define NGROUPS (2 * NCH)       // 128 (dir, nch) groups
#define POISON_U 0xAAAAAAAAu

__device__ __forceinline__ unsigned short f2bf(float f) {  // RTN-even
    unsigned int u = __float_as_uint(f);
    u += 0x7FFFu + ((u >> 16) & 1u);
    return (unsigned short)(u >> 16);
}
__device__ __forceinline__ float bf2f(unsigned short h) {
    return __uint_as_float(((unsigned int)h) << 16);
}
__device__ __forceinline__ unsigned int pk2(unsigned short a, unsigned short b) {
    return (unsigned int)a | ((unsigned int)b << 16);
}

struct Payload {
    unsigned short hx, hy, hz, lx, ly, lz, n1, n2, n3;
};
__device__ __forceinline__ Payload split_point(float x, float y, float z) {
    Payload P;
    P.hx = f2bf(x);  P.hy = f2bf(y);  P.hz = f2bf(z);
    P.lx = f2bf(x - bf2f(P.hx));
    P.ly = f2bf(y - bf2f(P.hy));
    P.lz = f2bf(z - bf2f(P.hz));
    float nrm = fmaf(z, z, fmaf(y, y, x * x));
    P.n1 = f2bf(nrm);
    float r1 = nrm - bf2f(P.n1);
    P.n2 = f2bf(r1);
    P.n3 = f2bf(r1 - bf2f(P.n2));
    return P;
}

__global__ __launch_bounds__(BLK) void chamfer_mega_kernel(
        const float* __restrict__ pred, const float* __restrict__ target,
        float* __restrict__ part, unsigned int* __restrict__ grpcnt,
        float* __restrict__ wsacc, unsigned int* __restrict__ gcnt,
        float* __restrict__ out)
{
    const int dir = blockIdx.z;
    const float* __restrict__ Q  = dir ? target : pred;   // outputs (B cols)
    const float* __restrict__ Tg = dir ? pred : target;   // min-over (A, LDS)

    const int nch = blockIdx.x;            // 0..63 (512-query-col chunk)
    const int b   = nch >> 4;              // batch (16 chunks per batch)
    const int ms  = blockIdx.y;            // 0..7 target slice
    const int w    = threadIdx.x >> 6;
    const int lane = threadIdx.x & 63;
    const int c = lane & 31;               // row (A) / col (B) within tile
    const int g = lane >> 5;               // k-half
    const unsigned short ONE = 0x3F80;

    __shared__ uint4 ldsb[2][MC];          // 32 KB (two k-halves)
    __shared__ float bsum[4];
    __shared__ int   fin;

    // ---- stage MC target points: raw read -> payload -> LDS (A operand) ----
    #pragma unroll
    for (int j = 0; j < MC / BLK; ++j) {
        int p = j * BLK + threadIdx.x;
        size_t gp = (size_t)b * NPTS + (size_t)ms * MC + p;
        float x = Tg[3 * gp], y = Tg[3 * gp + 1], z = Tg[3 * gp + 2];
        Payload P = split_point(x, y, z);
        ldsb[0][p] = (uint4){ pk2(P.hx, P.hy), pk2(P.hz, P.hx),
                              pk2(P.hy, P.hz), pk2(P.lx, P.ly) };
        ldsb[1][p] = (uint4){ pk2(P.lz, ONE), pk2(ONE, ONE),
                              pk2(P.n1, P.n2), pk2(P.n3, 0) };
    }

    // ---- B fragments (queries): in-register pack ----
    const int colstart = nch * BCOLS + w * (WNT * 32);
    short8 bq[WNT];
    #pragma unroll
    for (int nt = 0; nt < WNT; ++nt) {
        int r = colstart + nt * 32 + c;
        float x = Q[3 * r], y = Q[3 * r + 1], z = Q[3 * r + 2];
        Payload P = split_point(x, y, z);
        unsigned short ax = f2bf(-2.f * bf2f(P.hx)),
                       ay = f2bf(-2.f * bf2f(P.hy)),
                       az = f2bf(-2.f * bf2f(P.hz));
        unsigned short cx = f2bf(-2.f * bf2f(P.lx)),
                       cy = f2bf(-2.f * bf2f(P.ly)),
                       cz = f2bf(-2.f * bf2f(P.lz));
        uint4 h0 = { pk2(ax, ay), pk2(az, cx), pk2(cy, cz), pk2(ax, ay) };
        uint4 h1 = { pk2(az, P.n1), pk2(P.n2, P.n3), pk2(ONE, ONE), pk2(ONE, 0) };
        uint4 sel = g ? h1 : h0;
        bq[nt] = *(short8*)&sel;
    }

    f32x16 acc[WNT];
    #pragma unroll
    for (int nt = 0; nt < WNT; ++nt)
        #pragma unroll
        for (int r = 0; r < 16; ++r) acc[nt][r] = 3.4e38f;

    f32x16 vzero;
    #pragma unroll
    for (int r = 0; r < 16; ++r) vzero[r] = 0.0f;

    __syncthreads();

    const ushort* ldsu = (const ushort*)&ldsb[g][0];   // this lane's k-half

    // ---- main loop (R11, unchanged): 2 ds_read + 8 MFMA + 64 min3 ----
    #pragma unroll 2
    for (int mt = 0; mt < MT_PER; mt += 2) {
        short8 at0 = *(const short8*)(ldsu + (mt * 32 + c) * 8);
        short8 at1 = *(const short8*)(ldsu + ((mt + 1) * 32 + c) * 8);
        #pragma unroll
        for (int nt = 0; nt < WNT; ++nt) {
            f32x16 d0, d1;
            asm("v_mfma_f32_32x32x16_bf16 %0, %2, %4, %5\n\t"
                "v_mfma_f32_32x32x16_bf16 %1, %3, %4, %5\n\t"
                "s_nop 7\n\t"
                "s_nop 7"
                : "=&v"(d0), "=&v"(d1)
                : "v"(at0), "v"(at1), "v"(bq[nt]), "v"(vzero));
            #pragma unroll
            for (int r = 0; r < 16; ++r)
                acc[nt][r] = fminf(fminf(acc[nt][r], d0[r]), d1[r]); // v_min3
        }
    }

    // ---- epilogue: in-lane fold + 1 shfl; store slice partials ----
    float* rp = part + (size_t)(dir * MSPLIT + ms) * TOTALQ;
    #pragma unroll
    for (int nt = 0; nt < WNT; ++nt) {
        f32x16 v = acc[nt];
        float m0 = fminf(fminf(v[0],  v[1]),  fminf(v[2],  v[3]));
        float m1 = fminf(fminf(v[4],  v[5]),  fminf(v[6],  v[7]));
        float m2 = fminf(fminf(v[8],  v[9]),  fminf(v[10], v[11]));
        float m3 = fminf(fminf(v[12], v[13]), fminf(v[14], v[15]));
        float m  = fminf(fminf(m0, m1), fminf(m2, m3));
        m = fminf(m, __shfl_xor(m, 32, 64));    // fold the two k-half rows
        if (g == 0) rp[colstart + nt * 32 + c] = m;
    }

    // ---- group finalization: 8th block of (dir,nch) reduces the group ----
    __syncthreads();
    if (threadIdx.x == 0) {
        __threadfence();                                   // release stores
        unsigned int old = atomicAdd(&grpcnt[dir * NCH + nch], 1u);
        fin = (old == POISON_U + (MSPLIT - 1)) ? 1 : 0;
    }
    __syncthreads();
    if (!fin) return;

    __threadfence();                                       // acquire
    {
        float v = 0.0f;
        #pragma unroll
        for (int k = 0; k < BCOLS / BLK; ++k) {            // 2 queries/thread
            int qi = nch * BCOLS + k * BLK + threadIdx.x;
            const float* p = part + (size_t)dir * MSPLIT * TOTALQ + qi;
            float m = __hip_atomic_load(&p[0], __ATOMIC_RELAXED,
                                        __HIP_MEMORY_SCOPE_AGENT);
            #pragma unroll
            for (int s = 1; s < MSPLIT; ++s)
                m = fminf(m, __hip_atomic_load(&p[(size_t)s * TOTALQ],
                                               __ATOMIC_RELAXED,
                                               __HIP_MEMORY_SCOPE_AGENT));
            v += m;
        }
        v *= (1.0f / (float)TOTALQ);
        #pragma unroll
        for (int off = 32; off > 0; off >>= 1)
            v += __shfl_down(v, off, 64);
        if (lane == 0) bsum[w] = v;
    }
    __syncthreads();
    if (threadIdx.x == 0) {
        float s = (bsum[0] + bsum[1]) + (bsum[2] + bsum[3]);
        atomicAdd(wsacc, s);               // ws float poison -3e-13 ~ 0
        __threadfence();                   // release
        unsigned int old = atomicAdd(gcnt, 1u);            // poison-based
        if (old == POISON_U + (NGROUPS - 1)) {
            __threadfence();               // acquire
            out[0] = __hip_atomic_load(wsacc, __ATOMIC_RELAXED,
                                       __HIP_MEMORY_SCOPE_AGENT);
        }
    }
}

extern "C" void kernel_launch(void* const* d_in, const int* in_sizes, int n_in,
                              void* d_out, int out_size, void* d_ws, size_t ws_size,
                              hipStream_t stream) {
    const float*  pred   = (const float*)d_in[0];
    const float*  target = (const float*)d_in[1];
    float*        out    = (float*)d_out;
    float*        part   = (float*)d_ws;                  // 2 MB slice minima
    char*         tail   = (char*)d_ws + (size_t)2 * MSPLIT * TOTALQ * 4;
    unsigned int* grpcnt = (unsigned int*)tail;           // 128 uints (poison)
    float*        wsacc  = (float*)(tail + 512);          // poison ~ -3e-13
    unsigned int* gcnt   = (unsigned int*)(tail + 516);   // poison 0xAAAAAAAA

    dim3 grid(NCH, MSPLIT, 2);             // 64 x 8 x 2 = 1024 blocks
    hipLaunchKernelGGL(chamfer_mega_kernel, grid, dim3(BLK), 0, stream,
                       pred, target, part, grpcnt, wsacc, gcnt, out);
}

// Round 17
// 80.360 us; speedup vs baseline: 1.5155x; 1.2251x over previous
//
#include <hip/hip_runtime.h>
#include <hip/hip_bf16.h>

// Chamfer distance, B=4, N=M=8192, D=3, fp32.
// R16: occupancy attack on the proven R11/R13 kernel. R15 showed the asm
// main loop's VALU busy ~9 us (min3 model-exact) but dur ~21 us in the best
// config -> ~55% latency stall at 4 waves/SIMD. Halve LDS tile (MC=512,
// 16.5 KB) and double grid (MSPLIT=16 -> 2048 blocks -> 8 blocks/CU,
// ~7 waves/SIMD at VGPR=72) to hide the per-wave serial chain.
// Structure: TWO kernels (in-kernel finalization twice-falsified: per-block
// __threadfence = L2 writeback storm, R12/R15). Payload & loop unchanged
// (absmax 0.0 since R7).
//   payload k0..15 (target A x query B): -2h.h | -2l.h | -2h.l | qn.1 | 1.tn
// C/D 32x32 (m74/m101): col=lane&31, row=(reg&3)+8*(reg>>2)+4*(lane>>5).

typedef __attribute__((ext_vector_type(8)))  short short8;
typedef __attribute__((ext_vector_type(16))) float f32x16;

#define BATCH 4
#define NPTS 8192
#define TOTALQ (BATCH * NPTS)   // 32768
#define BLK 256
#define WNT 4                   // 32-col B tiles per wave -> 128 queries/wave
#define BCOLS 512               // query cols per block (4 waves)
#define NCH (TOTALQ / BCOLS)    // 64 query chunks
#define MSPLIT 16               // target slices per batch
#define MC (NPTS / MSPLIT)      // 512 targets per block, single LDS stage
#define MT_PER (MC / 32)        // 16 target tiles

__device__ __forceinline__ unsigned short f2bf(float f) {  // RTN-even
    unsigned int u = __float_as_uint(f);
    u += 0x7FFFu + ((u >> 16) & 1u);
    return (unsigned short)(u >> 16);
}
__device__ __forceinline__ float bf2f(unsigned short h) {
    return __uint_as_float(((unsigned int)h) << 16);
}
__device__ __forceinline__ unsigned int pk2(unsigned short a, unsigned short b) {
    return (unsigned int)a | ((unsigned int)b << 16);
}

struct Payload {
    unsigned short hx, hy, hz, lx, ly, lz, n1, n2, n3;
};
__device__ __forceinline__ Payload split_point(float x, float y, float z) {
    Payload P;
    P.hx = f2bf(x);  P.hy = f2bf(y);  P.hz = f2bf(z);
    P.lx = f2bf(x - bf2f(P.hx));
    P.ly = f2bf(y - bf2f(P.hy));
    P.lz = f2bf(z - bf2f(P.hz));
    float nrm = fmaf(z, z, fmaf(y, y, x * x));
    P.n1 = f2bf(nrm);
    float r1 = nrm - bf2f(P.n1);
    P.n2 = f2bf(r1);
    P.n3 = f2bf(r1 - bf2f(P.n2));
    return P;
}

__global__ __launch_bounds__(BLK) void chamfer_mega_kernel(
        const float* __restrict__ pred, const float* __restrict__ target,
        float* __restrict__ part, float* __restrict__ out)
{
    const int dir = blockIdx.z;
    const float* __restrict__ Q  = dir ? target : pred;   // outputs (B cols)
    const float* __restrict__ Tg = dir ? pred : target;   // min-over (A, LDS)

    const int nch = blockIdx.x;            // 0..63 (512-query-col chunk)
    const int b   = nch >> 4;              // batch (16 chunks per batch)
    const int ms  = blockIdx.y;            // 0..15 target slice
    const int w    = threadIdx.x >> 6;
    const int lane = threadIdx.x & 63;
    const int c = lane & 31;               // row (A) / col (B) within tile
    const int g = lane >> 5;               // k-half
    const unsigned short ONE = 0x3F80;

    if (blockIdx.x == 0 && blockIdx.y == 0 && blockIdx.z == 0 &&
        threadIdx.x == 0) out[0] = 0.0f;   // consumed after kernel boundary

    __shared__ uint4 ldsb[2][MC];          // 16 KB (two k-halves)

    // ---- stage MC target points: raw read -> payload -> LDS (A operand) ----
    #pragma unroll
    for (int j = 0; j < MC / BLK; ++j) {
        int p = j * BLK + threadIdx.x;
        size_t gp = (size_t)b * NPTS + (size_t)ms * MC + p;
        float x = Tg[3 * gp], y = Tg[3 * gp + 1], z = Tg[3 * gp + 2];
        Payload P = split_point(x, y, z);
        ldsb[0][p] = (uint4){ pk2(P.hx, P.hy), pk2(P.hz, P.hx),
                              pk2(P.hy, P.hz), pk2(P.lx, P.ly) };
        ldsb[1][p] = (uint4){ pk2(P.lz, ONE), pk2(ONE, ONE),
                              pk2(P.n1, P.n2), pk2(P.n3, 0) };
    }

    // ---- B fragments (queries): in-register pack ----
    const int colstart = nch * BCOLS + w * (WNT * 32);
    short8 bq[WNT];
    #pragma unroll
    for (int nt = 0; nt < WNT; ++nt) {
        int r = colstart + nt * 32 + c;
        float x = Q[3 * r], y = Q[3 * r + 1], z = Q[3 * r + 2];
        Payload P = split_point(x, y, z);
        unsigned short ax = f2bf(-2.f * bf2f(P.hx)),
                       ay = f2bf(-2.f * bf2f(P.hy)),
                       az = f2bf(-2.f * bf2f(P.hz));
        unsigned short cx = f2bf(-2.f * bf2f(P.lx)),
                       cy = f2bf(-2.f * bf2f(P.ly)),
                       cz = f2bf(-2.f * bf2f(P.lz));
        uint4 h0 = { pk2(ax, ay), pk2(az, cx), pk2(cy, cz), pk2(ax, ay) };
        uint4 h1 = { pk2(az, P.n1), pk2(P.n2, P.n3), pk2(ONE, ONE), pk2(ONE, 0) };
        uint4 sel = g ? h1 : h0;
        bq[nt] = *(short8*)&sel;
    }

    f32x16 acc[WNT];
    #pragma unroll
    for (int nt = 0; nt < WNT; ++nt)
        #pragma unroll
        for (int r = 0; r < 16; ++r) acc[nt][r] = 3.4e38f;

    f32x16 vzero;
    #pragma unroll
    for (int r = 0; r < 16; ++r) vzero[r] = 0.0f;

    __syncthreads();

    const ushort* ldsu = (const ushort*)&ldsb[g][0];   // this lane's k-half

    // ---- main loop (R11, unchanged): 2 ds_read + 8 MFMA + 64 min3 ----
    #pragma unroll 2
    for (int mt = 0; mt < MT_PER; mt += 2) {
        short8 at0 = *(const short8*)(ldsu + (mt * 32 + c) * 8);
        short8 at1 = *(const short8*)(ldsu + ((mt + 1) * 32 + c) * 8);
        #pragma unroll
        for (int nt = 0; nt < WNT; ++nt) {
            f32x16 d0, d1;
            asm("v_mfma_f32_32x32x16_bf16 %0, %2, %4, %5\n\t"
                "v_mfma_f32_32x32x16_bf16 %1, %3, %4, %5\n\t"
                "s_nop 7\n\t"
                "s_nop 7"
                : "=&v"(d0), "=&v"(d1)
                : "v"(at0), "v"(at1), "v"(bq[nt]), "v"(vzero));
            #pragma unroll
            for (int r = 0; r < 16; ++r)
                acc[nt][r] = fminf(fminf(acc[nt][r], d0[r]), d1[r]); // v_min3
        }
    }

    // ---- epilogue: in-lane fold + 1 shfl; store slice partials ----
    float* rp = part + (size_t)(dir * MSPLIT + ms) * TOTALQ;
    #pragma unroll
    for (int nt = 0; nt < WNT; ++nt) {
        f32x16 v = acc[nt];
        float m0 = fminf(fminf(v[0],  v[1]),  fminf(v[2],  v[3]));
        float m1 = fminf(fminf(v[4],  v[5]),  fminf(v[6],  v[7]));
        float m2 = fminf(fminf(v[8],  v[9]),  fminf(v[10], v[11]));
        float m3 = fminf(fminf(v[12], v[13]), fminf(v[14], v[15]));
        float m  = fminf(fminf(m0, m1), fminf(m2, m3));
        m = fminf(m, __shfl_xor(m, 32, 64));    // fold the two k-half rows
        if (g == 0) rp[colstart + nt * 32 + c] = m;
    }
}

__global__ __launch_bounds__(BLK) void chamfer_reduce_kernel(
        const float* __restrict__ part, float* __restrict__ out)
{
    int gl = blockIdx.x * BLK + threadIdx.x;   // 0..65535
    int dir = gl >> 15, i = gl & (TOTALQ - 1);

    const float* p = part + (size_t)dir * MSPLIT * TOTALQ + i;
    float m = p[0];
    #pragma unroll
    for (int s = 1; s < MSPLIT; ++s)
        m = fminf(m, p[(size_t)s * TOTALQ]);

    float acc = m * (1.0f / (float)TOTALQ);
    #pragma unroll
    for (int off = 32; off > 0; off >>= 1)
        acc += __shfl_down(acc, off, 64);
    __shared__ float wsum[BLK / 64];
    int lane = threadIdx.x & 63, wid = threadIdx.x >> 6;
    if (lane == 0) wsum[wid] = acc;
    __syncthreads();
    if (threadIdx.x == 0) {
        float s = 0.0f;
        #pragma unroll
        for (int wv = 0; wv < BLK / 64; ++wv) s += wsum[wv];
        atomicAdd(out, s);
    }
}

extern "C" void kernel_launch(void* const* d_in, const int* in_sizes, int n_in,
                              void* d_out, int out_size, void* d_ws, size_t ws_size,
                              hipStream_t stream) {
    const float* pred   = (const float*)d_in[0];
    const float* target = (const float*)d_in[1];
    float*       out    = (float*)d_out;
    float*       part   = (float*)d_ws;   // 2 dirs x 16 slices x 32768 = 4 MB

    dim3 grid(NCH, MSPLIT, 2);            // 64 x 16 x 2 = 2048 blocks
    hipLaunchKernelGGL(chamfer_mega_kernel, grid, dim3(BLK), 0, stream,
                       pred, target, part, out);

    hipLaunchKernelGGL(chamfer_reduce_kernel, dim3(2 * TOTALQ / BLK), dim3(BLK),
                       0, stream, (const float*)part, out);
}